// Round 8
// baseline (16.185 us; speedup 1.0000x reference)
//
#include <hip/hip_runtime.h>

typedef __fp16 h2 __attribute__((ext_vector_type(2)));   // matches cvt_pkrtz return

// Block = 64 n (lanes) x 4 b-waves, 4 b-iterations/thread.
// grid = (N/64, B/16) = 2048 blocks = 8 blocks/CU -> 32 waves/CU, enabled by
// keeping total regs <= 64: w row held as 32 packed f16 pairs (32 VGPRs),
// consumed by v_dot2_f32_f16 (2 MACs/instr, f32 accum).
// Factorization: idx i = b0b1 | b2b3 | b4b5 ->
//   out = sum_g t01[g] * sum_j t23[j] * fdot2-pairs(t45, w[g][j][:])
// Input read direct from global (LDS staging proven neutral in R3/R4),
// software-pipelined 2 deep, first loads issued before the sigma setup.
__global__ __launch_bounds__(256, 8) void lut_kernel(const float* __restrict__ in,
                                                     const float* __restrict__ lut,
                                                     float* __restrict__ out,
                                                     int N) {
    __shared__ __align__(16) __fp16 wsm[64][72];  // 144 B rows (pad for b128)

    const int t  = threadIdx.x;
    const int nl = t & 63;            // lane = local n
    const int wv = t >> 6;            // wave id 0..3 (parallel b)
    const int n0 = blockIdx.x * 64;
    const int n  = n0 + nl;
    const int b0 = blockIdx.y * 16 + wv;

    // ---- issue first two iterations' input loads immediately ----
    const float2* ip = reinterpret_cast<const float2*>(in) + ((size_t)b0 * N + n) * 3;
    const size_t st  = (size_t)N * 12;            // 4 b-rows in float2 units
    float2 pf[2][3];
    pf[0][0] = ip[0];      pf[0][1] = ip[1];      pf[0][2] = ip[2];
    pf[1][0] = ip[st + 0]; pf[1][1] = ip[st + 1]; pf[1][2] = ip[st + 2];

    // ---- sigmoid(lut) tile -> f16 LDS (coalesced float4 loads) ----
    {
        const float4* lp = reinterpret_cast<const float4*>(lut + (size_t)n0 * 64);
        const int rr = t >> 2, c4 = t & 3;
        #pragma unroll
        for (int p = 0; p < 4; ++p) {
            const int s = c4 + p * 4;             // float4 slot 0..15
            float4 v = lp[rr * 16 + s];           // wave: 4 KB contiguous
            h2 a = __builtin_amdgcn_cvt_pkrtz(1.0f / (1.0f + __expf(-v.x)),
                                              1.0f / (1.0f + __expf(-v.y)));
            h2 b = __builtin_amdgcn_cvt_pkrtz(1.0f / (1.0f + __expf(-v.z)),
                                              1.0f / (1.0f + __expf(-v.w)));
            *reinterpret_cast<h2*>(&wsm[rr][s * 4 + 0]) = a;
            *reinterpret_cast<h2*>(&wsm[rr][s * 4 + 2]) = b;
        }
    }
    __syncthreads();

    // ---- this thread's w row: 32 half2 (8 x ds_read_b128) ----
    h2 w2[32];
    #pragma unroll
    for (int k = 0; k < 8; ++k) {
        // 16 B = 8 halfs = 4 half2
        h2 r0 = *reinterpret_cast<const h2*>(&wsm[nl][k * 8 + 0]);
        h2 r1 = *reinterpret_cast<const h2*>(&wsm[nl][k * 8 + 2]);
        h2 r2 = *reinterpret_cast<const h2*>(&wsm[nl][k * 8 + 4]);
        h2 r3 = *reinterpret_cast<const h2*>(&wsm[nl][k * 8 + 6]);
        w2[k * 4 + 0] = r0; w2[k * 4 + 1] = r1;
        w2[k * 4 + 2] = r2; w2[k * 4 + 3] = r3;
    }

    float* op = out + (size_t)b0 * N + n;

    #pragma unroll
    for (int it = 0; it < 4; ++it) {
        const float2 va = pf[it & 1][0], vb = pf[it & 1][1], vc = pf[it & 1][2];
        if (it < 2) {
            const float2* np = ip + (size_t)(it + 2) * st;
            pf[it & 1][0] = np[0]; pf[it & 1][1] = np[1]; pf[it & 1][2] = np[2];
        }
        const float x0 = va.x, x1 = va.y, x2 = vb.x,
                    x3 = vb.y, x4 = vc.x, x5 = vc.y;
        const float B0 = 1.0f - x0, B1 = 1.0f - x1, B2 = 1.0f - x2,
                    B3 = 1.0f - x3, B4 = 1.0f - x4, B5 = 1.0f - x5;

        // bit==0 -> x, bit==1 -> (1-x); i = b0*32+b1*16 + b2*8+b3*4 + b4*2+b5
        const float t01a[4] = {x0 * x1, x0 * B1, B0 * x1, B0 * B1};
        const float t23a[4] = {x2 * x3, x2 * B3, B2 * x3, B2 * B3};
        // q0 = {x4*x5, x4*B5}, q1 = {B4*x5, B4*B5} packed f16
        const h2 q0 = __builtin_amdgcn_cvt_pkrtz(x4 * x5, x4 * B5);
        const h2 q1 = __builtin_amdgcn_cvt_pkrtz(B4 * x5, B4 * B5);

        float acc = 0.0f;
        #pragma unroll
        for (int g = 0; g < 4; ++g) {
            float sg = 0.0f;
            #pragma unroll
            for (int j = 0; j < 4; ++j) {
#if __has_builtin(__builtin_amdgcn_fdot2)
                float d = __builtin_amdgcn_fdot2(q0, w2[g * 8 + j * 2 + 0], 0.0f, false);
                d       = __builtin_amdgcn_fdot2(q1, w2[g * 8 + j * 2 + 1], d,    false);
#else
                const h2 wa = w2[g * 8 + j * 2 + 0], wb = w2[g * 8 + j * 2 + 1];
                float d = (float)q0.x * (float)wa.x + (float)q0.y * (float)wa.y
                        + (float)q1.x * (float)wb.x + (float)q1.y * (float)wb.y;
#endif
                sg = fmaf(t23a[j], d, sg);
            }
            acc = fmaf(t01a[g], sg, acc);
        }
        op[(size_t)it * 4 * N] = acc;
    }
}

extern "C" void kernel_launch(void* const* d_in, const int* in_sizes, int n_in,
                              void* d_out, int out_size, void* d_ws, size_t ws_size,
                              hipStream_t stream) {
    const float* inputs = (const float*)d_in[0];   // [B, N, 6] f32
    const float* lut    = (const float*)d_in[1];   // [N, 64]  f32
    float* out = (float*)d_out;                    // [B, N]   f32

    const int lut_sz = in_sizes[1];                // N*64
    const int N = lut_sz / 64;
    const int B = in_sizes[0] / (6 * N);

    dim3 grid(N / 64, B / 16);
    lut_kernel<<<grid, 256, 0, stream>>>(inputs, lut, out, N);
}